// Round 15
// baseline (218.218 us; speedup 1.0000x reference)
//
#include <hip/hip_runtime.h>
#include <hip/hip_bf16.h>

typedef unsigned short u16;
typedef unsigned int   u32;
typedef short  short8 __attribute__((ext_vector_type(8)));
typedef float  f32x4  __attribute__((ext_vector_type(4)));

#define NB    65536
#define XP    132
#define OFF1  ((size_t)NB * 128)
#define OFF2  (OFF1 + (size_t)NB * 4)

__device__ __forceinline__ u16 f2bf(float f) {
  __hip_bfloat16 b = __float2bfloat16(f);
  u16 u; __builtin_memcpy(&u, &b, 2); return u;
}
__device__ __forceinline__ float bf2f(u32 bits16) {
  union { u32 u; float f; } v; v.u = bits16 << 16; return v.f;
}
__device__ __forceinline__ u32 pk2(float a, float b) {
  return (u32)f2bf(a) | ((u32)f2bf(b) << 16);
}
__device__ __forceinline__ float red16(float v) {
  v += __shfl_xor(v, 1); v += __shfl_xor(v, 2);
  v += __shfl_xor(v, 4); v += __shfl_xor(v, 8);
  return v;
}
// completes all outstanding LDS ops; compiler memory barrier (no HW barrier)
__device__ __forceinline__ void lds_fence() {
  asm volatile("s_waitcnt lgkmcnt(0)" ::: "memory");
}

// ---------------- weight pre-pack: 10 x [128][128] fp32 -> bf16 MFMA-B-fragment order
// packed[t]: t = w*16384 + nt*2048 + kt*512 + lane*8 + j
//   holds W_w[kt*32 + (lane>>4)*8 + j][nt*16 + (lane&15)]
__global__ void pack_w(const float* __restrict__ proj_w,
                       const float* __restrict__ in_proj_w,
                       const float* __restrict__ out_w,
                       const float* __restrict__ gate_w,
                       u16* __restrict__ wp) {
  int t = blockIdx.x * 256 + threadIdx.x;
  if (t >= 10 * 16384) return;
  int w = t >> 14, i = t & 16383;
  int nt = i >> 11, kt = (i >> 9) & 3, ln = (i >> 3) & 63, j = i & 7;
  int k = kt * 32 + ((ln >> 4) << 3) + j;
  int n = (nt << 4) + (ln & 15);
  float v;
  if (w < 4)       v = proj_w[((size_t)w << 14) + (k << 7) + n];
  else if (w < 7)  v = in_proj_w[k * 384 + ((w - 4) << 7) + n];
  else if (w == 7) v = out_w[(k << 7) + n];
  else             v = gate_w[(((w - 8) << 7) + k) * 128 + n];
  wp[t] = f2bf(v);
}

// All 4 kt B-fragments of one (w, nt) loaded as a batch BEFORE the MFMA chain.
struct BF4 { short8 b[4]; };
__device__ __forceinline__ BF4 loadB4(const u16* __restrict__ wp, int w, int nt, int lane) {
  const u16* base = wp + ((size_t)w << 14) + ((size_t)(nt << 2) << 9) + ((size_t)lane << 3);
  BF4 r;
  #pragma unroll
  for (int kt = 0; kt < 4; ++kt)
    r.b[kt] = *(const short8*)(base + (kt << 9));
  return r;
}
struct AF { short8 a[4]; };
__device__ __forceinline__ AF loadA(const u16 (*Ab)[XP], int row, int lgrp) {
  AF r;
  #pragma unroll
  for (int kt = 0; kt < 4; ++kt)
    r.a[kt] = *(const short8*)&Ab[row][kt * 32 + (lgrp << 3)];
  return r;
}
__device__ __forceinline__ f32x4 mm4(const AF& A, const BF4& B, f32x4 acc) {
  #pragma unroll
  for (int kt = 0; kt < 4; ++kt)
    acc = __builtin_amdgcn_mfma_f32_16x16x32_bf16(A.a[kt], B.b[kt], acc, 0, 0, 0);
  return acc;
}

// One wave (64 threads) per 16-row tile. NO __syncthreads anywhere.
// R15 = R14 logic with ROLLED loops (#pragma unroll 1 on nt/s/h loops): code
// shrinks ~57KB -> ~10KB to fit the 32KB I$ (R14 diagnosis: straight-line
// giant kernel = every instruction fetched from L2 once, ~100K cy/wave).
// Per-nt state moved to LDS to avoid rule-#20 scratch (runtime-indexed reg
// arrays): x0 in xls[0] (no xcp0), q bf16 in scr (R13-validated), ao fp32 in
// aof, ctx logits in ctxl_lds. NT streaming kept. No min-waves bound (R8).
__global__ __launch_bounds__(64) void fused_k(
    const float* __restrict__ h0, const float* __restrict__ h1,
    const float* __restrict__ h2, const float* __restrict__ h3,
    const u16* __restrict__ wp,
    const float* __restrict__ proj_b, const float* __restrict__ ctx_w,
    const float* __restrict__ in_proj_b, const float* __restrict__ out_b,
    const float* __restrict__ gate_b, const float* __restrict__ pool_w,
    const float* __restrict__ ln_g, const float* __restrict__ ln_b,
    float* __restrict__ out) {
  __shared__ __align__(16) u16 xls[4][16][XP];   // x_s -> fused f_s
  __shared__ __align__(16) u16 scr[16][XP];      // context / q / o / attn_out scratch
  __shared__ __align__(16) float aof[16][132];   // attn_out fp32 (padded vs bank conflict)
  __shared__ float ctxl_lds[4][16];              // ctx logits
  __shared__ float awf[64];                      // attn_weights stage

  const int lane  = threadIdx.x;     // 0..63
  const int lrow  = lane & 15;       // A-row / C-col-within-chunk
  const int lgrp  = lane >> 4;
  const int crow0 = lgrp << 2;       // C rows 4*lgrp + j
  const size_t r0w = (size_t)blockIdx.x * 16;

  // ---- P0: per source (ROLLED): h A-frags (NT), proj GEMM -> xls, ctx logits -> LDS
  #pragma unroll 1
  for (int s = 0; s < 4; ++s) {
    const float* hs = (s == 0) ? h0 : (s == 1) ? h1 : (s == 2) ? h2 : h3;
    const float* __restrict__ hb = hs + ((r0w + lrow) << 7) + (lgrp << 3);
    AF Ah;
    #pragma unroll
    for (int kt = 0; kt < 4; ++kt) {
      f32x4 va = __builtin_nontemporal_load((const f32x4*)(hb + kt * 32));
      f32x4 vb = __builtin_nontemporal_load((const f32x4*)(hb + kt * 32 + 4));
      u32 tmp[4] = {pk2(va[0], va[1]), pk2(va[2], va[3]), pk2(vb[0], vb[1]), pk2(vb[2], vb[3])};
      __builtin_memcpy(&Ah.a[kt], tmp, 16);
    }
    float lp[4] = {0.f, 0.f, 0.f, 0.f};
    BF4 cb = loadB4(wp, s, 0, lane);
    #pragma unroll 1
    for (int nt = 0; nt < 8; ++nt) {
      BF4 nb = loadB4(wp, s, (nt + 1) & 7, lane);
      int n = (nt << 4) + lrow;
      float pb = proj_b[(s << 7) + n];
      f32x4 acc = {pb, pb, pb, pb};
      acc = mm4(Ah, cb, acc);
      float cwn = ctx_w[n];
      #pragma unroll
      for (int j = 0; j < 4; ++j) {
        lp[j] += acc[j] * cwn;
        xls[s][crow0 + j][n] = f2bf(acc[j]);
      }
      cb = nb;
    }
    #pragma unroll
    for (int j = 0; j < 4; ++j) lp[j] = red16(lp[j]);
    if (lrow == 0) {
      #pragma unroll
      for (int j = 0; j < 4; ++j) ctxl_lds[s][crow0 + j] = lp[j];
    }
  }
  lds_fence();
  AF Axs[4];
  #pragma unroll
  for (int s = 0; s < 4; ++s) Axs[s] = loadA(xls[s], lrow, lgrp);

  // ---- P1: ctx softmax (from LDS logits) + context -> scr
  float cw[4][4];
  #pragma unroll
  for (int j = 0; j < 4; ++j) {
    int row = crow0 + j;
    float l0 = ctxl_lds[0][row], l1 = ctxl_lds[1][row];
    float l2 = ctxl_lds[2][row], l3 = ctxl_lds[3][row];
    float mx = fmaxf(fmaxf(l0, l1), fmaxf(l2, l3));
    float e0 = __expf(l0 - mx), e1 = __expf(l1 - mx), e2 = __expf(l2 - mx), e3 = __expf(l3 - mx);
    float inv = 1.f / (e0 + e1 + e2 + e3);
    cw[0][j] = e0 * inv; cw[1][j] = e1 * inv; cw[2][j] = e2 * inv; cw[3][j] = e3 * inv;
  }
  #pragma unroll 1
  for (int nt = 0; nt < 8; ++nt) {
    int n = (nt << 4) + lrow;
    #pragma unroll
    for (int j = 0; j < 4; ++j) {
      float v = cw[0][j] * bf2f((u32)xls[0][crow0 + j][n])
              + cw[1][j] * bf2f((u32)xls[1][crow0 + j][n])
              + cw[2][j] * bf2f((u32)xls[2][crow0 + j][n])
              + cw[3][j] * bf2f((u32)xls[3][crow0 + j][n]);
      scr[crow0 + j][n] = f2bf(v);
    }
  }
  lds_fence();
  AF Ac = loadA(scr, lrow, lgrp);

  // ---- P2: q = context @ wq + bq -> scr (bf16, overwrites context; R13-validated)
  {
    BF4 cb = loadB4(wp, 4, 0, lane);
    #pragma unroll 1
    for (int nt = 0; nt < 8; ++nt) {
      BF4 nb = loadB4(wp, 4, (nt + 1) & 7, lane);
      int n = (nt << 4) + lrow;
      float bq = in_proj_b[n];
      f32x4 acc = {bq, bq, bq, bq};
      acc = mm4(Ac, cb, acc);
      #pragma unroll
      for (int j = 0; j < 4; ++j) scr[crow0 + j][n] = f2bf(acc[j]);
      cb = nb;
    }
  }
  lds_fence();

  // ---- P3+P5 per head (ROLLED): K GEMM + scores + softmax + V GEMM; o overwrites q cols
  float awm[4][4] = {};
  #pragma unroll 1
  for (int h = 0; h < 4; ++h) {
    float sch[4][4] = {};
    #pragma unroll
    for (int t = 0; t < 2; ++t) {
      int nt = (h << 1) + t, n = (nt << 4) + lrow;
      BF4 B = loadB4(wp, 5, nt, lane);
      float bk = in_proj_b[128 + n];
      f32x4 ak[4];
      #pragma unroll
      for (int s = 0; s < 4; ++s) ak[s] = (f32x4){bk, bk, bk, bk};
      #pragma unroll
      for (int kt = 0; kt < 4; ++kt)
        #pragma unroll
        for (int s = 0; s < 4; ++s)
          ak[s] = __builtin_amdgcn_mfma_f32_16x16x32_bf16(Axs[s].a[kt], B.b[kt], ak[s], 0, 0, 0);
      float qv[4];
      #pragma unroll
      for (int j = 0; j < 4; ++j) qv[j] = bf2f((u32)scr[crow0 + j][n]);
      #pragma unroll
      for (int s = 0; s < 4; ++s)
        #pragma unroll
        for (int j = 0; j < 4; ++j)
          sch[s][j] += ak[s][j] * qv[j];
    }
    #pragma unroll
    for (int s = 0; s < 4; ++s)
      #pragma unroll
      for (int j = 0; j < 4; ++j)
        sch[s][j] = red16(sch[s][j]);
    float awh[4][4];
    #pragma unroll
    for (int j = 0; j < 4; ++j) {
      const float scale = 0.17677669529663687f;  // 1/sqrt(32)
      float l0 = sch[0][j] * scale, l1 = sch[1][j] * scale;
      float l2 = sch[2][j] * scale, l3 = sch[3][j] * scale;
      float mx = fmaxf(fmaxf(l0, l1), fmaxf(l2, l3));
      float e0 = __expf(l0 - mx), e1 = __expf(l1 - mx), e2 = __expf(l2 - mx), e3 = __expf(l3 - mx);
      float inv = 1.f / (e0 + e1 + e2 + e3);
      awh[0][j] = e0 * inv; awh[1][j] = e1 * inv;
      awh[2][j] = e2 * inv; awh[3][j] = e3 * inv;
      awm[0][j] += awh[0][j]; awm[1][j] += awh[1][j];
      awm[2][j] += awh[2][j]; awm[3][j] += awh[3][j];
    }
    #pragma unroll
    for (int t = 0; t < 2; ++t) {
      int nt = (h << 1) + t, n = (nt << 4) + lrow;
      BF4 B = loadB4(wp, 6, nt, lane);
      float bv = in_proj_b[256 + n];
      f32x4 av[4];
      #pragma unroll
      for (int s = 0; s < 4; ++s) av[s] = (f32x4){bv, bv, bv, bv};
      #pragma unroll
      for (int kt = 0; kt < 4; ++kt)
        #pragma unroll
        for (int s = 0; s < 4; ++s)
          av[s] = __builtin_amdgcn_mfma_f32_16x16x32_bf16(Axs[s].a[kt], B.b[kt], av[s], 0, 0, 0);
      #pragma unroll
      for (int j = 0; j < 4; ++j) {
        float o = awh[0][j] * av[0][j] + awh[1][j] * av[1][j]
                + awh[2][j] * av[2][j] + awh[3][j] * av[3][j];
        scr[crow0 + j][n] = f2bf(o);
      }
    }
  }
  lds_fence();
  AF Ao = loadA(scr, lrow, lgrp);

  // ---- attn_weights out
  if (lrow == 0) {
    #pragma unroll
    for (int s = 0; s < 4; ++s)
      #pragma unroll
      for (int j = 0; j < 4; ++j)
        awf[((crow0 + j) << 2) + s] = 0.25f * awm[s][j];
  }
  lds_fence();
  __builtin_nontemporal_store(awf[lane], &out[OFF1 + (r0w << 2) + lane]);

  // ---- P6: attn_out = o @ out_w + out_b -> scr (bf16 for Aa) + aof (fp32)
  {
    BF4 cb = loadB4(wp, 7, 0, lane);
    #pragma unroll 1
    for (int nt = 0; nt < 8; ++nt) {
      BF4 nb = loadB4(wp, 7, (nt + 1) & 7, lane);
      int n = (nt << 4) + lrow;
      float bo = out_b[n];
      f32x4 acc = {bo, bo, bo, bo};
      acc = mm4(Ao, cb, acc);
      #pragma unroll
      for (int j = 0; j < 4; ++j) {
        scr[crow0 + j][n] = f2bf(acc[j]);
        aof[crow0 + j][n] = acc[j];
      }
      cb = nb;
    }
  }
  lds_fence();
  AF Aa = loadA(scr, lrow, lgrp);

  // ---- P7 (ROLLED): gate = gate_b + ao@W9 + x@W8 (fp32 chain), sigmoid, fuse
  float sm[4][4] = {}, sq[4][4] = {};
  #pragma unroll 1
  for (int nt = 0; nt < 8; ++nt) {
    int n = (nt << 4) + lrow;
    BF4 c9 = loadB4(wp, 9, nt, lane);
    BF4 c8 = loadB4(wp, 8, nt, lane);
    float gb = gate_b[n];
    f32x4 tt = {gb, gb, gb, gb};
    tt = mm4(Aa, c9, tt);
    float aov[4];
    #pragma unroll
    for (int j = 0; j < 4; ++j) aov[j] = aof[crow0 + j][n];
    #pragma unroll
    for (int s = 0; s < 4; ++s) {
      f32x4 acc = mm4(Axs[s], c8, tt);
      #pragma unroll
      for (int j = 0; j < 4; ++j) {
        float g = 1.f / (1.f + __expf(-acc[j]));
        __builtin_nontemporal_store(g, &out[OFF2 + (((r0w + crow0 + j) << 2) + s) * 128 + n]);
        float xv = bf2f((u32)xls[s][crow0 + j][n]);
        float f = g * aov[j] + (1.f - g) * xv;
        sm[s][j] += f;
        sq[s][j] += f * f;
        xls[s][crow0 + j][n] = f2bf(f);   // overwrite x with fused
      }
    }
  }
  float mean_[4][4], rstd_[4][4];
  #pragma unroll
  for (int s = 0; s < 4; ++s)
    #pragma unroll
    for (int j = 0; j < 4; ++j) {
      float ts = red16(sm[s][j]);
      float tq = red16(sq[s][j]);
      float mean = ts * 0.0078125f;
      float var  = tq * 0.0078125f - mean * mean;
      mean_[s][j] = mean;
      rstd_[s][j] = rsqrtf(var + 1e-5f);
    }

  // ---- P8 (ROLLED): pool logits (fp32 fn from bf16 f) + softmax + pooled out
  float pp[4][4] = {};
  #pragma unroll 1
  for (int nt = 0; nt < 8; ++nt) {
    int n = (nt << 4) + lrow;
    float lng = ln_g[n], lnb = ln_b[n], pwv = pool_w[n];
    #pragma unroll
    for (int s = 0; s < 4; ++s)
      #pragma unroll
      for (int j = 0; j < 4; ++j) {
        float f  = bf2f((u32)xls[s][crow0 + j][n]);
        float fn = (f - mean_[s][j]) * rstd_[s][j] * lng + lnb;
        pp[s][j] += fn * pwv;
      }
  }
  float pw[4][4];
  #pragma unroll
  for (int j = 0; j < 4; ++j) {
    float l0 = red16(pp[0][j]), l1 = red16(pp[1][j]);
    float l2 = red16(pp[2][j]), l3 = red16(pp[3][j]);
    float mx = fmaxf(fmaxf(l0, l1), fmaxf(l2, l3));
    float e0 = __expf(l0 - mx), e1 = __expf(l1 - mx), e2 = __expf(l2 - mx), e3 = __expf(l3 - mx);
    float inv = 1.f / (e0 + e1 + e2 + e3);
    pw[0][j] = e0 * inv; pw[1][j] = e1 * inv; pw[2][j] = e2 * inv; pw[3][j] = e3 * inv;
  }
  #pragma unroll 1
  for (int nt = 0; nt < 8; ++nt) {
    int n = (nt << 4) + lrow;
    float lng = ln_g[n], lnb = ln_b[n];
    #pragma unroll
    for (int j = 0; j < 4; ++j) {
      float acc = 0.f;
      #pragma unroll
      for (int s = 0; s < 4; ++s) {
        float f  = bf2f((u32)xls[s][crow0 + j][n]);
        float fn = (f - mean_[s][j]) * rstd_[s][j] * lng + lnb;
        acc += pw[s][j] * fn;
      }
      __builtin_nontemporal_store(acc, &out[((r0w + crow0 + j) << 7) + n]);
    }
  }
}

extern "C" void kernel_launch(void* const* d_in, const int* in_sizes, int n_in,
                              void* d_out, int out_size, void* d_ws, size_t ws_size,
                              hipStream_t stream) {
  const float* h0        = (const float*)d_in[0];
  const float* h1        = (const float*)d_in[1];
  const float* h2        = (const float*)d_in[2];
  const float* h3        = (const float*)d_in[3];
  const float* proj_w    = (const float*)d_in[4];
  const float* proj_b    = (const float*)d_in[5];
  const float* ctx_w     = (const float*)d_in[6];
  const float* in_proj_w = (const float*)d_in[8];
  const float* in_proj_b = (const float*)d_in[9];
  const float* out_w     = (const float*)d_in[10];
  const float* out_b     = (const float*)d_in[11];
  const float* gate_w    = (const float*)d_in[12];
  const float* gate_b    = (const float*)d_in[13];
  const float* pool_w    = (const float*)d_in[14];
  const float* ln_g      = (const float*)d_in[16];
  const float* ln_b      = (const float*)d_in[17];
  u16* wp = (u16*)d_ws;

  pack_w<<<640, 256, 0, stream>>>(proj_w, in_proj_w, out_w, gate_w, wp);
  fused_k<<<NB / 16, 64, 0, stream>>>(h0, h1, h2, h3, wp,
                                      proj_b, ctx_w, in_proj_b, out_b, gate_b,
                                      pool_w, ln_g, ln_b, (float*)d_out);
}